// Round 3
// baseline (618.921 us; speedup 1.0000x reference)
//
#include <hip/hip_runtime.h>
#include <stdint.h>

#define T_TOK 8192
#define HDIM  2048
#define NEXP  8
#define BM    256
#define BN    256
#define BK    64            // k-elems per LDS tile; 8 chunks of 8 bf16 per row
#define RTOK  32            // tokens per router block

typedef __bf16 bf16x8 __attribute__((ext_vector_type(8)));
typedef float  f32x4  __attribute__((ext_vector_type(4)));
typedef unsigned short u16;
typedef u16    u16x8  __attribute__((ext_vector_type(8)));

typedef const __attribute__((address_space(1))) void* gptr_t;
typedef __attribute__((address_space(3))) void* lptr_t;

static __device__ __forceinline__ u16 f2bf(float f) {
    union { float f; unsigned u; } v; v.f = f;
    unsigned u = v.u;
    u = (u + 0x7FFFu + ((u >> 16) & 1u)) >> 16;   // RNE
    return (u16)u;
}

// fp32 -> bf16, 8 elems/thread (weights only; x is converted in router)
__global__ __launch_bounds__(256) void cvt_kernel(const float* __restrict__ in,
                                                  u16* __restrict__ out, int n8) {
    int i = blockIdx.x * 256 + threadIdx.x;
    if (i >= n8) return;
    const float4* p = (const float4*)in + (size_t)i * 2;
    float4 a = p[0], b = p[1];
    u16x8 r;
    r[0] = f2bf(a.x); r[1] = f2bf(a.y); r[2] = f2bf(a.z); r[3] = f2bf(a.w);
    r[4] = f2bf(b.x); r[5] = f2bf(b.y); r[6] = f2bf(b.z); r[7] = f2bf(b.w);
    ((u16x8*)out)[i] = r;
}

// Router: 32 tokens/block (4 waves x 8 tokens). Computes logits, top-2,
// converts x->bf16 on the fly, and scatters via per-block LDS lists +
// 8 global atomics per block.
__global__ __launch_bounds__(256) void router_kernel(const float* __restrict__ x,
                                                     const float* __restrict__ gw,
                                                     u16* __restrict__ xb,
                                                     float* __restrict__ logits_out,
                                                     int* __restrict__ cnt,
                                                     int* __restrict__ rows,
                                                     float* __restrict__ wts) {
    __shared__ int   lcnt[NEXP];
    __shared__ int   lbase[NEXP];
    __shared__ int   lrows[NEXP][RTOK];
    __shared__ float lwtsS[NEXP][RTOK];

    int tid  = threadIdx.x;
    int lane = tid & 63;
    int wave = tid >> 6;
    if (tid < NEXP) lcnt[tid] = 0;
    __syncthreads();

    int t0 = blockIdx.x * RTOK + wave * 8;
    const float4* g4 = (const float4*)gw;

    float acc[8][NEXP] = {};
    #pragma unroll
    for (int i = 0; i < HDIM / 4 / 64; i++) {      // 8 iters
        int idx = lane + i * 64;
        float4 gv[NEXP];
        #pragma unroll
        for (int e = 0; e < NEXP; e++) gv[e] = g4[e * (HDIM / 4) + idx];
        #pragma unroll
        for (int tk = 0; tk < 8; tk++) {
            int t = t0 + tk;
            float4 xv = ((const float4*)(x + (size_t)t * HDIM))[idx];
            ushort4 h;
            h.x = f2bf(xv.x); h.y = f2bf(xv.y); h.z = f2bf(xv.z); h.w = f2bf(xv.w);
            ((ushort4*)(xb + (size_t)t * HDIM))[idx] = h;
            #pragma unroll
            for (int e = 0; e < NEXP; e++)
                acc[tk][e] += xv.x * gv[e].x + xv.y * gv[e].y +
                              xv.z * gv[e].z + xv.w * gv[e].w;
        }
    }
    #pragma unroll
    for (int tk = 0; tk < 8; tk++)
        #pragma unroll
        for (int e = 0; e < NEXP; e++)
            #pragma unroll
            for (int off = 32; off > 0; off >>= 1)
                acc[tk][e] += __shfl_xor(acc[tk][e], off, 64);

    if (lane == 0) {
        #pragma unroll
        for (int tk = 0; tk < 8; tk++) {
            int t = t0 + tk;
            #pragma unroll
            for (int e = 0; e < NEXP; e++) logits_out[(size_t)t * NEXP + e] = acc[tk][e];
            int e0 = 0;
            #pragma unroll
            for (int e = 1; e < NEXP; e++) if (acc[tk][e] > acc[tk][e0]) e0 = e;
            int e1 = (e0 == 0) ? 1 : 0;
            #pragma unroll
            for (int e = 0; e < NEXP; e++)
                if (e != e0 && acc[tk][e] > acc[tk][e1]) e1 = e;
            float w0 = 1.0f / (1.0f + expf(acc[tk][e1] - acc[tk][e0]));
            int p0 = atomicAdd(&lcnt[e0], 1);
            lrows[e0][p0] = t; lwtsS[e0][p0] = w0;
            int p1 = atomicAdd(&lcnt[e1], 1);
            lrows[e1][p1] = t; lwtsS[e1][p1] = 1.0f - w0;
        }
    }
    __syncthreads();
    if (tid < NEXP) lbase[tid] = atomicAdd(&cnt[tid], lcnt[tid]);
    __syncthreads();
    int e = tid >> 5, j = tid & 31;                 // 8 experts x 32 slots
    if (j < lcnt[e]) {
        int b = lbase[e] + j;
        rows[e * T_TOK + b] = lrows[e][j];
        wts[e * T_TOK + b]  = lwtsS[e][j];
    }
}

// grouped GEMM, 256x256 tile (8 waves, 2Mx4N), BK=64, XCD swizzle,
// depth-2 pipeline with COUNTED vmcnt (T3+T4, verified structure from
// the 128^2 version — parameter change only): each K-step waits vmcnt(8)
// ("my current tile's 8 loads landed, next tile's 8 stay in flight"),
// never drains to 0 inside the loop. Raw s_barrier + sched_barrier(0).
// LDS 128 KB (2 x 32 KB A + 2 x 32 KB B) -> 1 block/CU; latency hiding
// is in-block (64-MFMA chain per wave per K-step).
__global__ __launch_bounds__(512, 2) void moe_gemm(const u16* __restrict__ xb,
                                                   const u16* __restrict__ wb,
                                                   const int* __restrict__ cnt,
                                                   const int* __restrict__ rows,
                                                   const float* __restrict__ wts,
                                                   float* __restrict__ out) {
    int p  = blockIdx.x;
    int xc = p & 7;
    int q  = p >> 3;
    int rt = q & 31;                 // rowtile 0..31
    int g  = (q >> 5) * 8 + xc;      // 0..63 = expert*8 + coltile
    int e  = g >> 3;
    int nb = (g & 7) * BN;

    int count = cnt[e];
    int rowBase = rt * BM;
    if (rowBase >= count) return;

    const u16*   W     = wb  + (size_t)e * HDIM * HDIM;
    const int*   rlist = rows + e * T_TOK;
    const float* wlist = wts  + e * T_TOK;

    __shared__ u16 As[2][BM * BK];   // 2 x 32 KB
    __shared__ u16 Bs[2][BM * BK];   // 2 x 32 KB  -> 128 KB total

    int tid  = threadIdx.x;          // 0..511
    int lane = tid & 63;
    int wave = tid >> 6;             // 0..7
    int wr = wave >> 2, wc = wave & 3;

    // staging: round l stages slot (l*512 + tid); row = slot>>3 (0..255),
    // stored chunk = slot&7, logical chunk = (slot&7)^(row&7)
    const u16* a_src[4];
    const u16* b_src[4];
    #pragma unroll
    for (int l = 0; l < 4; l++) {
        int row  = (tid >> 3) + l * 64;             // 0..255
        int clog = (tid & 7) ^ (row & 7);
        int tok  = rlist[min(rowBase + row, count - 1)];
        a_src[l] = xb + (size_t)tok * HDIM + clog * 8;
        b_src[l] = W + (size_t)(nb + row) * HDIM + clog * 8;
    }
    int wslot = (tid & ~63);                        // wave-uniform

    // 8 global_load_lds per thread per K-tile (4 A + 4 B) = 8 vmcnt slots
    auto stage = [&](u16* A_lds, u16* B_lds, int kb) {
        #pragma unroll
        for (int l = 0; l < 4; l++) {
            __builtin_amdgcn_global_load_lds((gptr_t)(a_src[l] + kb),
                                             (lptr_t)(A_lds + (l * 512 + wslot) * 8),
                                             16, 0, 0);
            __builtin_amdgcn_global_load_lds((gptr_t)(b_src[l] + kb),
                                             (lptr_t)(B_lds + (l * 512 + wslot) * 8),
                                             16, 0, 0);
        }
    };

    int lrow = lane & 15;
    int kq   = lane >> 4;
    int mloc[8], nloc[4];
    #pragma unroll
    for (int i = 0; i < 8; i++) mloc[i] = wr * 128 + i * 16 + lrow;
    #pragma unroll
    for (int j = 0; j < 4; j++) nloc[j] = wc * 64 + j * 16 + lrow;

    f32x4 acc[8][4] = {};

    auto compute = [&](const u16* A_lds, const u16* B_lds) {
        #pragma unroll
        for (int s = 0; s < 2; s++) {
            int chunk = s * 4 + kq;
            bf16x8 a[8], b[4];
            #pragma unroll
            for (int i = 0; i < 8; i++) {
                int aslot = (mloc[i] << 3) | (chunk ^ (mloc[i] & 7));
                a[i] = *(const bf16x8*)(A_lds + aslot * 8);
            }
            #pragma unroll
            for (int j = 0; j < 4; j++) {
                int bslot = (nloc[j] << 3) | (chunk ^ (nloc[j] & 7));
                b[j] = *(const bf16x8*)(B_lds + bslot * 8);
            }
            #pragma unroll
            for (int i = 0; i < 8; i++)
                #pragma unroll
                for (int j = 0; j < 4; j++)
                    acc[i][j] = __builtin_amdgcn_mfma_f32_16x16x32_bf16(
                                    a[i], b[j], acc[i][j], 0, 0, 0);
        }
    };

    // ---- depth-2 counted-vmcnt pipeline over 32 K-tiles ----
    stage(As[0], Bs[0], 0);
    stage(As[1], Bs[1], BK);

    for (int kb = 0; kb < HDIM - 2 * BK; kb += 2 * BK) {
        asm volatile("s_waitcnt vmcnt(8)" ::: "memory");
        __builtin_amdgcn_sched_barrier(0);
        __builtin_amdgcn_s_barrier();              // tile t data visible to all
        compute(As[0], Bs[0]);
        __builtin_amdgcn_sched_barrier(0);
        __builtin_amdgcn_s_barrier();              // all waves done reading buf0
        stage(As[0], Bs[0], kb + 2 * BK);

        asm volatile("s_waitcnt vmcnt(8)" ::: "memory");
        __builtin_amdgcn_sched_barrier(0);
        __builtin_amdgcn_s_barrier();
        compute(As[1], Bs[1]);
        __builtin_amdgcn_sched_barrier(0);
        __builtin_amdgcn_s_barrier();              // all waves done reading buf1
        stage(As[1], Bs[1], kb + 3 * BK);
    }
    // tile 30
    asm volatile("s_waitcnt vmcnt(8)" ::: "memory");
    __builtin_amdgcn_sched_barrier(0);
    __builtin_amdgcn_s_barrier();
    compute(As[0], Bs[0]);
    // tile 31 (drain)
    asm volatile("s_waitcnt vmcnt(0)" ::: "memory");
    __builtin_amdgcn_sched_barrier(0);
    __builtin_amdgcn_s_barrier();
    compute(As[1], Bs[1]);

    int srow = (lane >> 4) * 4;
    #pragma unroll
    for (int i = 0; i < 8; i++) {
        #pragma unroll
        for (int r = 0; r < 4; r++) {
            int row = rowBase + wr * 128 + i * 16 + srow + r;
            if (row < count) {
                int   tok = rlist[row];
                float wgt = wlist[row];
                #pragma unroll
                for (int j = 0; j < 4; j++) {
                    int col = nb + wc * 64 + j * 16 + lrow;
                    atomicAdd(out + (size_t)tok * HDIM + col, wgt * acc[i][j][r]);
                }
            }
        }
    }
}

extern "C" void kernel_launch(void* const* d_in, const int* in_sizes, int n_in,
                              void* d_out, int out_size, void* d_ws, size_t ws_size,
                              hipStream_t stream) {
    const float* x  = (const float*)d_in[0];   // [T, H]
    const float* gw = (const float*)d_in[1];   // [E, H]
    const float* ew = (const float*)d_in[2];   // [E, H, H]
    float* out    = (float*)d_out;             // [T, H] fp32
    float* logits = out + (size_t)T_TOK * HDIM;

    char* ws = (char*)d_ws;
    int*   cnt  = (int*)ws;                                   // 32 B
    int*   rows = (int*)(ws + 1024);                          // 256 KB
    float* wts  = (float*)(ws + 1024 + 262144);               // 256 KB
    u16*   xb   = (u16*)(ws + 1024 + 2 * 262144);             // 32 MB
    u16*   wb   = xb + (size_t)T_TOK * HDIM;                  // 64 MB

    hipMemsetAsync(d_out, 0, (size_t)T_TOK * HDIM * sizeof(float), stream);
    hipMemsetAsync(cnt, 0, NEXP * sizeof(int), stream);

    int nw8 = NEXP * HDIM * HDIM / 8;
    cvt_kernel<<<(nw8 + 255) / 256, 256, 0, stream>>>(ew, wb, nw8);

    router_kernel<<<T_TOK / RTOK, 256, 0, stream>>>(x, gw, xb, logits, cnt, rows, wts);

    moe_gemm<<<NEXP * 32 * 8, 512, 0, stream>>>(xb, wb, cnt, rows, wts, out);
}

// Round 4
// 607.269 us; speedup vs baseline: 1.0192x; 1.0192x over previous
//
#include <hip/hip_runtime.h>
#include <stdint.h>

#define T_TOK 8192
#define HDIM  2048
#define NEXP  8
#define BM    256
#define BN    256
#define BK    64            // k-elems per LDS tile; 8 chunks of 8 bf16 per row
#define RTOK  32            // tokens per router block

typedef __bf16 bf16x8 __attribute__((ext_vector_type(8)));
typedef float  f32x4  __attribute__((ext_vector_type(4)));
typedef unsigned short u16;
typedef u16    u16x8  __attribute__((ext_vector_type(8)));

typedef const __attribute__((address_space(1))) void* gptr_t;
typedef __attribute__((address_space(3))) void* lptr_t;

static __device__ __forceinline__ u16 f2bf(float f) {
    union { float f; unsigned u; } v; v.f = f;
    unsigned u = v.u;
    u = (u + 0x7FFFu + ((u >> 16) & 1u)) >> 16;   // RNE
    return (u16)u;
}

// fp32 -> bf16, 8 elems/thread (weights only; x is converted in router)
__global__ __launch_bounds__(256) void cvt_kernel(const float* __restrict__ in,
                                                  u16* __restrict__ out, int n8) {
    int i = blockIdx.x * 256 + threadIdx.x;
    if (i >= n8) return;
    const float4* p = (const float4*)in + (size_t)i * 2;
    float4 a = p[0], b = p[1];
    u16x8 r;
    r[0] = f2bf(a.x); r[1] = f2bf(a.y); r[2] = f2bf(a.z); r[3] = f2bf(a.w);
    r[4] = f2bf(b.x); r[5] = f2bf(b.y); r[6] = f2bf(b.z); r[7] = f2bf(b.w);
    ((u16x8*)out)[i] = r;
}

// Router: 32 tokens/block (4 waves x 8 tokens). Computes logits, top-2,
// converts x->bf16 on the fly, and scatters via per-block LDS lists +
// 8 global atomics per block.
__global__ __launch_bounds__(256) void router_kernel(const float* __restrict__ x,
                                                     const float* __restrict__ gw,
                                                     u16* __restrict__ xb,
                                                     float* __restrict__ logits_out,
                                                     int* __restrict__ cnt,
                                                     int* __restrict__ rows,
                                                     float* __restrict__ wts) {
    __shared__ int   lcnt[NEXP];
    __shared__ int   lbase[NEXP];
    __shared__ int   lrows[NEXP][RTOK];
    __shared__ float lwtsS[NEXP][RTOK];

    int tid  = threadIdx.x;
    int lane = tid & 63;
    int wave = tid >> 6;
    if (tid < NEXP) lcnt[tid] = 0;
    __syncthreads();

    int t0 = blockIdx.x * RTOK + wave * 8;
    const float4* g4 = (const float4*)gw;

    float acc[8][NEXP] = {};
    #pragma unroll
    for (int i = 0; i < HDIM / 4 / 64; i++) {      // 8 iters
        int idx = lane + i * 64;
        float4 gv[NEXP];
        #pragma unroll
        for (int e = 0; e < NEXP; e++) gv[e] = g4[e * (HDIM / 4) + idx];
        #pragma unroll
        for (int tk = 0; tk < 8; tk++) {
            int t = t0 + tk;
            float4 xv = ((const float4*)(x + (size_t)t * HDIM))[idx];
            ushort4 h;
            h.x = f2bf(xv.x); h.y = f2bf(xv.y); h.z = f2bf(xv.z); h.w = f2bf(xv.w);
            ((ushort4*)(xb + (size_t)t * HDIM))[idx] = h;
            #pragma unroll
            for (int e = 0; e < NEXP; e++)
                acc[tk][e] += xv.x * gv[e].x + xv.y * gv[e].y +
                              xv.z * gv[e].z + xv.w * gv[e].w;
        }
    }
    #pragma unroll
    for (int tk = 0; tk < 8; tk++)
        #pragma unroll
        for (int e = 0; e < NEXP; e++)
            #pragma unroll
            for (int off = 32; off > 0; off >>= 1)
                acc[tk][e] += __shfl_xor(acc[tk][e], off, 64);

    if (lane == 0) {
        #pragma unroll
        for (int tk = 0; tk < 8; tk++) {
            int t = t0 + tk;
            #pragma unroll
            for (int e = 0; e < NEXP; e++) logits_out[(size_t)t * NEXP + e] = acc[tk][e];
            int e0 = 0;
            #pragma unroll
            for (int e = 1; e < NEXP; e++) if (acc[tk][e] > acc[tk][e0]) e0 = e;
            int e1 = (e0 == 0) ? 1 : 0;
            #pragma unroll
            for (int e = 0; e < NEXP; e++)
                if (e != e0 && acc[tk][e] > acc[tk][e1]) e1 = e;
            float w0 = 1.0f / (1.0f + expf(acc[tk][e1] - acc[tk][e0]));
            int p0 = atomicAdd(&lcnt[e0], 1);
            lrows[e0][p0] = t; lwtsS[e0][p0] = w0;
            int p1 = atomicAdd(&lcnt[e1], 1);
            lrows[e1][p1] = t; lwtsS[e1][p1] = 1.0f - w0;
        }
    }
    __syncthreads();
    if (tid < NEXP) lbase[tid] = atomicAdd(&cnt[tid], lcnt[tid]);
    __syncthreads();
    int e = tid >> 5, j = tid & 31;                 // 8 experts x 32 slots
    if (j < lcnt[e]) {
        int b = lbase[e] + j;
        rows[e * T_TOK + b] = lrows[e][j];
        wts[e * T_TOK + b]  = lwtsS[e][j];
    }
}

// grouped GEMM, 256x256 tile, 8 waves (2Mx4N), BK=64, XCD swizzle,
// 8-phase-style schedule (T3+T4+T5) with half-region LDS recycling:
//   - LDS split [dbuf][half]; wave (wr,wc) reads only A-half wr and
//     B-half wc>>1 of the current dbuf.
//   - per tile t: stage A(t+1) -> other dbuf at phase 1; stage B(t+2)
//     -> current dbuf's B region after the post-P1 barrier (B region is
//     block-wide free then: all b-reads happen in P1, lgkmcnt-drained).
//   - top-of-tile wait = vmcnt(4): leaves B(t+2)'s 4 loads in flight,
//     NEVER drains in the main loop. Cover: A = 1 tile, B = 2 tiles.
//   - setprio(1) around each 16-MFMA cluster (T5: pays only with
//     phase-split schedules, m218b).
__global__ __launch_bounds__(512, 2) void moe_gemm(const u16* __restrict__ xb,
                                                   const u16* __restrict__ wb,
                                                   const int* __restrict__ cnt,
                                                   const int* __restrict__ rows,
                                                   const float* __restrict__ wts,
                                                   float* __restrict__ out) {
    int p  = blockIdx.x;
    int xc = p & 7;
    int q  = p >> 3;
    int rt = q & 31;                 // rowtile 0..31
    int g  = (q >> 5) * 8 + xc;      // 0..63 = expert*8 + coltile
    int e  = g >> 3;
    int nb = (g & 7) * BN;

    int count = cnt[e];
    int rowBase = rt * BM;
    if (rowBase >= count) return;

    const u16*   W     = wb  + (size_t)e * HDIM * HDIM;
    const int*   rlist = rows + e * T_TOK;
    const float* wlist = wts  + e * T_TOK;

    __shared__ u16 As[2][2][128 * BK];   // [dbuf][half] 16 KB each -> 64 KB
    __shared__ u16 Bs[2][2][128 * BK];   // 64 KB                   -> 128 KB

    int tid  = threadIdx.x;          // 0..511
    int lane = tid & 63;
    int wave = tid >> 6;             // 0..7
    int wr = wave >> 2, wc = wave & 3;
    int wslot = tid & ~63;           // wave-uniform

    // staging sources: half h, round l covers rows h*128 + l*64 + (tid>>3).
    // stored chunk = tid&7 at slot l*512+tid; logical chunk = (tid&7)^(row&7)
    // (row&7 == (tid>>3)&7 since half/round offsets are multiples of 8).
    const u16* a_src[2][2];
    const u16* b_src[2][2];
    int clog = ((tid & 7) ^ ((tid >> 3) & 7)) * 8;
    #pragma unroll
    for (int h = 0; h < 2; h++)
        #pragma unroll
        for (int l = 0; l < 2; l++) {
            int row = h * 128 + l * 64 + (tid >> 3);
            int tok = rlist[min(rowBase + row, count - 1)];
            a_src[h][l] = xb + (size_t)tok * HDIM + clog;
            b_src[h][l] = W + (size_t)(nb + row) * HDIM + clog;
        }

    // stage one 128-row half (2 x global_load_lds = 2 vmcnt slots/thread)
    auto stageA = [&](int d, int h, int kb) {
        #pragma unroll
        for (int l = 0; l < 2; l++)
            __builtin_amdgcn_global_load_lds((gptr_t)(a_src[h][l] + kb),
                (lptr_t)(&As[d][h][(l * 512 + wslot) * 8]), 16, 0, 0);
    };
    auto stageB = [&](int d, int h, int kb) {
        #pragma unroll
        for (int l = 0; l < 2; l++)
            __builtin_amdgcn_global_load_lds((gptr_t)(b_src[h][l] + kb),
                (lptr_t)(&Bs[d][h][(l * 512 + wslot) * 8]), 16, 0, 0);
    };

    int lrow = lane & 15;
    int kq   = lane >> 4;

    f32x4  acc[8][4] = {};
    bf16x8 breg[4][2];

    // load the wave's full B slice for tile in dbuf C (8 ds_read_b128)
    auto loadB = [&](int C) {
        #pragma unroll
        for (int j = 0; j < 4; j++)
            #pragma unroll
            for (int s = 0; s < 2; s++) {
                int col = (wc & 1) * 64 + j * 16 + lrow;
                breg[j][s] = *(const bf16x8*)(&Bs[C][wc >> 1]
                    [(size_t)(((col) << 3) | ((s * 4 + kq) ^ (col & 7))) * 8]);
            }
    };

// one m-phase: 4 ds_read_b128 (a-frags I0,I0+1) + 16 MFMA, setprio-wrapped.
// All acc/As indices compile-time after expansion (rule #20).
#define MPHASE(C, I0) do {                                                     \
    bf16x8 a0_[2], a1_[2];                                                     \
    _Pragma("unroll") for (int s = 0; s < 2; s++) {                            \
        int r0 = (I0) * 16 + lrow, r1 = ((I0) + 1) * 16 + lrow;                \
        a0_[s] = *(const bf16x8*)(&As[C][wr]                                   \
            [(size_t)((r0 << 3) | ((s * 4 + kq) ^ (r0 & 7))) * 8]);            \
        a1_[s] = *(const bf16x8*)(&As[C][wr]                                   \
            [(size_t)((r1 << 3) | ((s * 4 + kq) ^ (r1 & 7))) * 8]);            \
    }                                                                          \
    __builtin_amdgcn_s_setprio(1);                                             \
    _Pragma("unroll") for (int j = 0; j < 4; j++)                              \
        _Pragma("unroll") for (int s = 0; s < 2; s++) {                        \
            acc[(I0)][j]     = __builtin_amdgcn_mfma_f32_16x16x32_bf16(        \
                                   a0_[s], breg[j][s], acc[(I0)][j], 0, 0, 0); \
            acc[(I0) + 1][j] = __builtin_amdgcn_mfma_f32_16x16x32_bf16(        \
                                   a1_[s], breg[j][s], acc[(I0) + 1][j], 0, 0, 0); \
        }                                                                      \
    __builtin_amdgcn_s_setprio(0);                                             \
} while (0)

// one K-tile: top wait vmcnt(VN) (4 in steady state, 0 at drain),
// stage-A(t+1) inside P1, stage-B(t+2) after the mid barrier.
#define PERIOD(C, KB, SA, SB, VN) do {                                         \
    asm volatile("s_waitcnt vmcnt(" #VN ") lgkmcnt(0)" ::: "memory");          \
    __builtin_amdgcn_sched_barrier(0);                                         \
    __builtin_amdgcn_s_barrier();                                              \
    __builtin_amdgcn_sched_barrier(0);                                         \
    if (SA) { stageA(1 - (C), 0, (KB) + BK); stageA(1 - (C), 1, (KB) + BK); }  \
    loadB(C);                                                                  \
    MPHASE(C, 0);                                                              \
    asm volatile("s_waitcnt lgkmcnt(0)" ::: "memory");                         \
    __builtin_amdgcn_sched_barrier(0);                                         \
    __builtin_amdgcn_s_barrier();                                              \
    __builtin_amdgcn_sched_barrier(0);                                         \
    if (SB) { stageB(C, 0, (KB) + 2 * BK); stageB(C, 1, (KB) + 2 * BK); }      \
    MPHASE(C, 2);                                                              \
    MPHASE(C, 4);                                                              \
    MPHASE(C, 6);                                                              \
} while (0)

    // prologue: A(0),B(0) then B(1) -> vmcnt(4) at tile 0 leaves B(1) in flight
    stageA(0, 0, 0);  stageA(0, 1, 0);
    stageB(0, 0, 0);  stageB(0, 1, 0);
    stageB(1, 0, BK); stageB(1, 1, BK);

    // main loop: tiles 0..29 (15 x 2), all stages unconditional & in range
    for (int kb = 0; kb < HDIM - 2 * BK; kb += 2 * BK) {
        PERIOD(0, kb, 1, 1, 4);
        PERIOD(1, kb + BK, 1, 1, 4);
    }
    // tile 30: stage A(31) only; tile 31: drain
    PERIOD(0, HDIM - 2 * BK, 1, 0, 4);
    PERIOD(1, HDIM - BK, 0, 0, 0);

#undef PERIOD
#undef MPHASE

    int srow = (lane >> 4) * 4;
    #pragma unroll
    for (int i = 0; i < 8; i++) {
        #pragma unroll
        for (int r = 0; r < 4; r++) {
            int row = rowBase + wr * 128 + i * 16 + srow + r;
            if (row < count) {
                int   tok = rlist[row];
                float wgt = wlist[row];
                #pragma unroll
                for (int j = 0; j < 4; j++) {
                    int col = nb + wc * 64 + j * 16 + lrow;
                    atomicAdd(out + (size_t)tok * HDIM + col, wgt * acc[i][j][r]);
                }
            }
        }
    }
}

extern "C" void kernel_launch(void* const* d_in, const int* in_sizes, int n_in,
                              void* d_out, int out_size, void* d_ws, size_t ws_size,
                              hipStream_t stream) {
    const float* x  = (const float*)d_in[0];   // [T, H]
    const float* gw = (const float*)d_in[1];   // [E, H]
    const float* ew = (const float*)d_in[2];   // [E, H, H]
    float* out    = (float*)d_out;             // [T, H] fp32
    float* logits = out + (size_t)T_TOK * HDIM;

    char* ws = (char*)d_ws;
    int*   cnt  = (int*)ws;                                   // 32 B
    int*   rows = (int*)(ws + 1024);                          // 256 KB
    float* wts  = (float*)(ws + 1024 + 262144);               // 256 KB
    u16*   xb   = (u16*)(ws + 1024 + 2 * 262144);             // 32 MB
    u16*   wb   = xb + (size_t)T_TOK * HDIM;                  // 64 MB

    hipMemsetAsync(d_out, 0, (size_t)T_TOK * HDIM * sizeof(float), stream);
    hipMemsetAsync(cnt, 0, NEXP * sizeof(int), stream);

    int nw8 = NEXP * HDIM * HDIM / 8;
    cvt_kernel<<<(nw8 + 255) / 256, 256, 0, stream>>>(ew, wb, nw8);

    router_kernel<<<T_TOK / RTOK, 256, 0, stream>>>(x, gw, xb, logits, cnt, rows, wts);

    moe_gemm<<<NEXP * 32 * 8, 512, 0, stream>>>(xb, wb, cnt, rows, wts, out);
}